// Round 2
// baseline (187.946 us; speedup 1.0000x reference)
//
#include <hip/hip_runtime.h>
#include <hip/hip_bf16.h>

#define MSEQ 2048

typedef __attribute__((ext_vector_type(8))) short short8;
typedef __attribute__((ext_vector_type(4))) short short4v;
typedef __attribute__((ext_vector_type(4))) float f32x4;

static __device__ __forceinline__ short bf16b(float f) {
    __hip_bfloat16 h = __float2bfloat16(f);   // RNE
    return *reinterpret_cast<short*>(&h);
}

// raw 2^x (input is pre-scaled by log2e at the K projection)
static __device__ __forceinline__ float fast_exp2(float x) {
    float r;
    asm("v_exp_f32 %0, %1" : "=v"(r) : "v"(x));
    return r;
}

// 16x16x16 bf16 MFMA (DQK=16 exact; D-layout matches PV A-frag layout)
static __device__ __forceinline__ f32x4 mfma16(short4v a, short4v b, f32x4 c) {
    return __builtin_amdgcn_mfma_f32_16x16x16bf16_1k(a, b, c, 0, 0, 0);
}

// async global->LDS, 16B per lane; LDS dest = wave-uniform base + lane*16
static __device__ __forceinline__ void gl_lds16(const void* g, void* l) {
    __builtin_amdgcn_global_load_lds(
        (const __attribute__((address_space(1))) unsigned int*)g,
        (__attribute__((address_space(3))) unsigned int*)l, 16, 0, 0);
}

// ---------------- x fp32 -> bf16 ----------------
__global__ __launch_bounds__(256) void xcvt_kernel(
    const float* __restrict__ x, unsigned short* __restrict__ xb)
{
    const size_t i = ((size_t)blockIdx.x * 256 + threadIdx.x) * 8;
    const float4 a = *(const float4*)(x + i);
    const float4 b = *(const float4*)(x + i + 4);
    short8 o;
    o[0]=bf16b(a.x); o[1]=bf16b(a.y); o[2]=bf16b(a.z); o[3]=bf16b(a.w);
    o[4]=bf16b(b.x); o[5]=bf16b(b.y); o[6]=bf16b(b.z); o[7]=bf16b(b.w);
    *(short8*)(xb + i) = o;
}

// ---------------- W -> WT[n][k] bf16 (n: 0..127 Wq | 128..255 Wk | 256..767 Wv) ----------------
__global__ __launch_bounds__(256) void wtrans_kernel(
    const float* __restrict__ Wq, const float* __restrict__ Wk,
    const float* __restrict__ Wv, unsigned short* __restrict__ WT)
{
    const int nt = blockIdx.x;   // 12 tiles of 64 n
    const int kt = blockIdx.y;   // 8 tiles of 64 k
    const int t  = threadIdx.x;
    const int k0 = kt*64;

    const float* W; int ld, n0;
    if (nt < 2)      { W = Wq; ld = 128; n0 = nt*64; }
    else if (nt < 4) { W = Wk; ld = 128; n0 = (nt-2)*64; }
    else             { W = Wv; ld = 512; n0 = (nt-4)*64; }

    __shared__ unsigned short Ts[64*72];   // [n][k], 144B rows

    #pragma unroll
    for (int s = 0; s < 4; ++s) {
        const int lin = s*256 + t;
        const int krow = lin >> 4, ng = lin & 15;
        const float4 v = *(const float4*)(W + (size_t)(k0+krow)*ld + n0 + ng*4);
        Ts[(ng*4+0)*72 + krow] = (unsigned short)bf16b(v.x);
        Ts[(ng*4+1)*72 + krow] = (unsigned short)bf16b(v.y);
        Ts[(ng*4+2)*72 + krow] = (unsigned short)bf16b(v.z);
        Ts[(ng*4+3)*72 + krow] = (unsigned short)bf16b(v.w);
    }
    __syncthreads();
    #pragma unroll
    for (int s = 0; s < 2; ++s) {
        const int lin = s*256 + t;
        const int nrow = lin >> 3, kg = lin & 7;
        *(short8*)(WT + (size_t)(nt*64 + nrow)*512 + k0 + kg*8) = *(const short8*)&Ts[nrow*72 + kg*8];
    }
}

// ---------------- Fused projection GEMM, bf16 MFMA ----------------
// nt==1 (K) output is pre-scaled by 0.25*log2(e) so attn can use raw v_exp_f32
// (exp(relu(0.25*qk)) == 2^relu(0.25*log2e*qk); relu commutes with the positive scale).
__global__ __launch_bounds__(256, 2) void proj_mfma(
    const unsigned short* __restrict__ xb, const unsigned short* __restrict__ WT,
    const float* __restrict__ bq, const float* __restrict__ bk, const float* __restrict__ bv,
    unsigned short* __restrict__ Qb, unsigned short* __restrict__ Kb, unsigned short* __restrict__ Vt)
{
    const int nt = blockIdx.x;        // 0..5 (0=Q,1=K,2..5=V)
    const int r0 = blockIdx.y * 128;  // m
    const int n0 = nt * 128;
    const int t = threadIdx.x, w = t >> 6, lane = t & 63, l15 = lane & 15, quad = lane >> 4;
    const int qh = w >> 1, chh = w & 1;

    __shared__ short smem[128*136];   // As/Bs alias the front, Ts uses all
    short* As = smem;                 // [128 m][32 k]
    short* Bs = smem + 128*32;        // [128 n][32 k]

    f32x4 acc[4][4];
    #pragma unroll
    for (int i = 0; i < 4; ++i)
        #pragma unroll
        for (int j = 0; j < 4; ++j) acc[i][j] = {0.f,0.f,0.f,0.f};

    const int arow = lane >> 2, akg = lane & 3;

    for (int kk = 0; kk < 512; kk += 32) {
        #pragma unroll
        for (int s = 0; s < 2; ++s) {
            const int row = w*32 + s*16 + arow;
            gl_lds16(xb + (size_t)(r0+row)*512 + kk + akg*8, As + (w*32 + s*16)*32);
            gl_lds16(WT + (size_t)(n0+row)*512 + kk + akg*8, Bs + (w*32 + s*16)*32);
        }
        __syncthreads();
        short8 Af[4], Bf[4];
        #pragma unroll
        for (int i = 0; i < 4; ++i) Af[i] = *(const short8*)&As[(qh*64 + i*16 + l15)*32 + quad*8];
        #pragma unroll
        for (int j = 0; j < 4; ++j) Bf[j] = *(const short8*)&Bs[(chh*64 + j*16 + l15)*32 + quad*8];
        #pragma unroll
        for (int i = 0; i < 4; ++i)
            #pragma unroll
            for (int j = 0; j < 4; ++j)
                acc[i][j] = __builtin_amdgcn_mfma_f32_16x16x32_bf16(Af[i], Bf[j], acc[i][j], 0, 0, 0);
        __syncthreads();
    }

    const float* bias = (nt == 0) ? bq : (nt == 1) ? bk : (bv + (nt-2)*128);
    const float kscale = (nt == 1) ? 0.36067376022224085f : 1.0f;  // 0.25 * log2(e)
    float bj[4];
    #pragma unroll
    for (int j = 0; j < 4; ++j) bj[j] = bias[chh*64 + j*16 + l15];

    short* Ts = smem;   // [128][136]
    if (nt < 2) {       // row-major [m][n]
        #pragma unroll
        for (int i = 0; i < 4; ++i)
            #pragma unroll
            for (int j = 0; j < 4; ++j)
                #pragma unroll
                for (int r = 0; r < 4; ++r)
                    Ts[(qh*64 + i*16 + quad*4 + r)*136 + chh*64 + j*16 + l15] =
                        bf16b((acc[i][j][r] + bj[j]) * kscale);
    } else {            // transposed [n][m] = [ch][key]
        #pragma unroll
        for (int i = 0; i < 4; ++i)
            #pragma unroll
            for (int j = 0; j < 4; ++j)
                #pragma unroll
                for (int r = 0; r < 4; ++r)
                    Ts[(chh*64 + j*16 + l15)*136 + qh*64 + i*16 + quad*4 + r] =
                        bf16b(acc[i][j][r] + bj[j]);
    }
    __syncthreads();

    if (nt < 2) {
        unsigned short* Out = (nt == 0) ? Qb : Kb;
        #pragma unroll
        for (int s = 0; s < 8; ++s) {
            const int lin = s*256 + t, row = lin >> 4, seg = lin & 15;
            *(short8*)(Out + (size_t)(r0+row)*128 + seg*8) = *(const short8*)&Ts[row*136 + seg*8];
        }
    } else {
        const int b = r0 >> 11, key0 = r0 & 2047, chBase = (nt-2)*128;
        #pragma unroll
        for (int s = 0; s < 8; ++s) {
            const int lin = s*256 + t, row = lin >> 4, seg = lin & 15;
            *(short8*)(Vt + ((size_t)(b*512 + chBase + row))*MSEQ + key0 + seg*8) =
                *(const short8*)&Ts[row*136 + seg*8];
        }
    }
}

// ---------------- Fused masked attention: register-resident, barrier-free loop ----------------
// 16x16x16 MFMA (DQK=16 exact). Swapped QK (A=K,B=Q): D holds S^T with
// lane(l15,quad) = {q=l15, keys=quad*4+r} — exactly the A-frag layout the PV MFMA
// needs, so P never touches LDS. K/Q/V/mask fragments are direct 8-16B global
// loads (L2-resident). Waves partition the 2048 keys 4-way; zero barriers in the
// loop; one cross-wave f32 reduction at the end.
__global__ __launch_bounds__(256, 4) void attn_mfma(
    const unsigned short* __restrict__ Qb, const unsigned short* __restrict__ Kb,
    const unsigned short* __restrict__ Vt, const int* __restrict__ mask,
    const float* __restrict__ gamma, float* __restrict__ out)
{
    const int bh = blockIdx.x;       // 32
    const int b  = bh >> 3, h = bh & 7;
    const int m0 = blockIdx.y * 64;  // 32 q-tiles of 64
    const int t  = threadIdx.x;
    const int w = t >> 6, lane = t & 63, l15 = lane & 15, quad = lane >> 4;

    // Q fragments: lane(l15,quad) = Q[m0 + c*16 + l15][h*16 + quad*4 ..+3]
    short4v qf[4];
    #pragma unroll
    for (int c = 0; c < 4; ++c)
        qf[c] = *(const short4v*)(Qb + (size_t)(b*MSEQ + m0 + c*16 + l15)*128 + h*16 + quad*4);

    f32x4 O[4][4];
    #pragma unroll
    for (int c = 0; c < 4; ++c)
        #pragma unroll
        for (int v = 0; v < 4; ++v) O[c][v] = {0.f,0.f,0.f,0.f};
    float ws_acc[4] = {0.f,0.f,0.f,0.f};

    // wave w owns keys [w*512, w*512+512)
    const unsigned short* Kp = Kb + (size_t)(b*MSEQ + w*512 + l15)*128 + h*16 + quad*4;
    const unsigned short* Vp = Vt + ((size_t)(b*512 + h*64 + l15))*MSEQ + w*512 + quad*4;
    const int* mp = mask + b*MSEQ + w*512 + quad*4;

    #pragma unroll 2
    for (int s = 0; s < 32; ++s) {
        const int kn = s*16;
        const short4v kf = *(const short4v*)(Kp + (size_t)kn*128);
        const int4 mk = *(const int4*)(mp + kn);
        short4v vf[4];
        #pragma unroll
        for (int v = 0; v < 4; ++v)
            vf[v] = *(const short4v*)(Vp + (size_t)v*16*MSEQ + kn);

        #pragma unroll
        for (int c = 0; c < 4; ++c) {
            f32x4 sc = {0.f,0.f,0.f,0.f};
            sc = mfma16(kf, qf[c], sc);
            // K pre-scaled by 0.25*log2e -> weight = mask * 2^max(s,0)
            const float w0 = mk.x ? fast_exp2(fmaxf(sc[0], 0.f)) : 0.f;
            const float w1 = mk.y ? fast_exp2(fmaxf(sc[1], 0.f)) : 0.f;
            const float w2 = mk.z ? fast_exp2(fmaxf(sc[2], 0.f)) : 0.f;
            const float w3 = mk.w ? fast_exp2(fmaxf(sc[3], 0.f)) : 0.f;
            ws_acc[c] += (w0 + w1) + (w2 + w3);
            short4v pf;
            pf[0]=bf16b(w0); pf[1]=bf16b(w1); pf[2]=bf16b(w2); pf[3]=bf16b(w3);
            #pragma unroll
            for (int v = 0; v < 4; ++v)
                O[c][v] = mfma16(pf, vf[v], O[c][v]);
        }
    }

    // ---- cross-wave reduction ----
    __shared__ float OsA[64*68];     // stride 68 floats: quad rows land on distinct banks
    __shared__ float OsB[64*68];
    __shared__ float wsl[4*64];
    __shared__ float wsums[64];

    #pragma unroll
    for (int c = 0; c < 4; ++c) {
        float r = ws_acc[c];
        r += __shfl_xor(r, 16, 64);
        r += __shfl_xor(r, 32, 64);
        if (quad == 0) wsl[w*64 + c*16 + l15] = r;
    }

    // phase 0: waves 0,2 write their partials
    if (w == 0 || w == 2) {
        float* buf = (w == 2) ? OsB : OsA;
        #pragma unroll
        for (int c = 0; c < 4; ++c)
            #pragma unroll
            for (int v = 0; v < 4; ++v)
                #pragma unroll
                for (int r = 0; r < 4; ++r)
                    buf[(c*16 + quad*4 + r)*68 + v*16 + l15] = O[c][v][r];
    }
    __syncthreads();
    // phase 1: waves 1,3 accumulate; thread 0-63 folds wsum partials
    if (w == 1 || w == 3) {
        float* buf = (w == 3) ? OsB : OsA;
        #pragma unroll
        for (int c = 0; c < 4; ++c)
            #pragma unroll
            for (int v = 0; v < 4; ++v)
                #pragma unroll
                for (int r = 0; r < 4; ++r)
                    buf[(c*16 + quad*4 + r)*68 + v*16 + l15] += O[c][v][r];
    }
    if (t < 64) wsums[t] = (wsl[t] + wsl[64+t]) + (wsl[128+t] + wsl[192+t]);
    __syncthreads();

    const float g = gamma[0];
    #pragma unroll
    for (int s2 = 0; s2 < 4; ++s2) {
        const int lin = s2*256 + t;        // 0..1023
        const int q = lin >> 4, seg = lin & 15;
        const float inv = g / fmaxf(wsums[q], 1e-20f);
        const int o = q*68 + seg*4;
        float4 vv;
        vv.x = (OsA[o+0] + OsB[o+0]) * inv;
        vv.y = (OsA[o+1] + OsB[o+1]) * inv;
        vv.z = (OsA[o+2] + OsB[o+2]) * inv;
        vv.w = (OsA[o+3] + OsB[o+3]) * inv;
        *(float4*)(out + (size_t)(b*MSEQ + m0 + q)*512 + h*64 + seg*4) = vv;
    }
}

extern "C" void kernel_launch(void* const* d_in, const int* in_sizes, int n_in,
                              void* d_out, int out_size, void* d_ws, size_t ws_size,
                              hipStream_t stream) {
    const float* x     = (const float*)d_in[0];
    const int*   mask  = (const int*)  d_in[1];
    const float* Wq    = (const float*)d_in[2];
    const float* bq    = (const float*)d_in[3];
    const float* Wk    = (const float*)d_in[4];
    const float* bk    = (const float*)d_in[5];
    const float* Wv    = (const float*)d_in[6];
    const float* bv    = (const float*)d_in[7];
    const float* gamma = (const float*)d_in[8];
    float* outp = (float*)d_out;

    // ws (bf16 shorts): xb 8MB | WT 0.75MB | Qb 2MB | Kb 2MB | Vt 8MB
    unsigned short* xb = (unsigned short*)d_ws;
    unsigned short* WT = xb + (size_t)8192*512;
    unsigned short* Qb = WT + (size_t)768*512;
    unsigned short* Kb = Qb + (size_t)8192*128;
    unsigned short* Vt = Kb + (size_t)8192*128;

    xcvt_kernel<<<2048, 256, 0, stream>>>(x, xb);
    wtrans_kernel<<<dim3(12, 8), 256, 0, stream>>>(Wq, Wk, Wv, WT);
    proj_mfma<<<dim3(6, 64), 256, 0, stream>>>(xb, WT, bq, bk, bv, Qb, Kb, Vt);
    attn_mfma<<<dim3(32, 32), 256, 0, stream>>>(Qb, Kb, Vt, mask, gamma, outp);
}